// Round 6
// baseline (582.288 us; speedup 1.0000x reference)
//
#include <hip/hip_runtime.h>

typedef _Float16 f16;
typedef _Float16 f16x2 __attribute__((ext_vector_type(2)));
typedef _Float16 f16x4 __attribute__((ext_vector_type(4)));
typedef _Float16 f16x8 __attribute__((ext_vector_type(8)));
typedef float f32x4 __attribute__((ext_vector_type(4)));

#define KM 0.1f   // DT * TAU_MEM_INV
#define KS 0.8f   // 1 - DT * TAU_SYN_INV
#define AS1 __attribute__((address_space(1)))
#define AS3 __attribute__((address_space(3)))
#define EPS_LO 2.44140625e-4f  // 2^-12

// ---------- merged weight prep ----------
// k<=1: interleaved W2[2*Np][Kp]: 16-row blocks alternate hi/lo.
// k>=2: separate whi/wlo (gemm_hilo layout).
struct PrepArgs {
  const float* W[6];
  f16* dsth[6];
  f16* dstl[6];
  int Nr[6], Kr[6], Kp[6], Npd[6];
  int boff[7];
  int inter[6];
};

__global__ void prep_w_all(PrepArgs a) {
  int blk = blockIdx.x;
  int k = 0;
#pragma unroll
  for (int j = 0; j < 5; ++j) k += (blk >= a.boff[j + 1]) ? 1 : 0;
  int i = (blk - a.boff[k]) * 256 + threadIdx.x;
  int Kp = a.Kp[k];
  int kp4 = Kp >> 2;
  int total4 = a.Npd[k] * kp4;
  if (i >= total4) return;
  int o = i / kp4, f = (i - o * kp4) << 2;
  float w[4] = {0.f, 0.f, 0.f, 0.f};
  if (o < a.Nr[k] && f < a.Kr[k]) {  // Kr % 4 == 0 -> float4 fully in-range
    float4 t = *(const float4*)&a.W[k][(size_t)o * a.Kr[k] + f];
    w[0] = t.x; w[1] = t.y; w[2] = t.z; w[3] = t.w;
  }
  f16x4 h4, l4;
#pragma unroll
  for (int e = 0; e < 4; ++e) {
    f16 h = (f16)w[e];
    float hf = (float)h;
    if (__builtin_fabsf(hf) < 6.103515625e-05f) { h = (f16)0.f; hf = 0.f; }
    h4[e] = h;
    l4[e] = (f16)((w[e] - hf) * 4096.0f);
  }
  if (a.inter[k]) {
    int r2 = ((o >> 4) << 5) + (o & 15);  // hi block; +16 rows = lo block
    *(f16x4*)&a.dsth[k][(size_t)r2 * Kp + f] = h4;
    *(f16x4*)&a.dsth[k][(size_t)(r2 + 16) * Kp + f] = l4;
  } else {
    *(f16x4*)&a.dsth[k][(size_t)o * Kp + f] = h4;
    *(f16x4*)&a.dstl[k][(size_t)o * Kp + f] = l4;
  }
}

// ---------- encoder + LIF0, 2 features per thread ----------
__global__ void enc_lif0(const float* __restrict__ img, f16* __restrict__ S0) {
  int idx = blockIdx.x * 256 + threadIdx.x;
  if (idx >= 128 * 6016) return;
  int b = idx / 6016, f = (idx - b * 6016) << 1;
  float x0 = 0.f, x1 = 0.f;
  if (f < 12000) {
    float2 t = *(const float2*)&img[b * 12000 + f];
    x0 = t.x; x1 = t.y;
  }
  float ve0 = 0.f, vl0 = 0.f, il0 = 0.f;
  float ve1 = 0.f, vl1 = 0.f, il1 = 0.f;
  size_t base = (size_t)b * 12032 + f;
  for (int t = 0; t < 32; ++t) {
    ve0 = ve0 + KM * (x0 - ve0);
    ve1 = ve1 + KM * (x1 - ve1);
    float z0a = (ve0 > 1.0f) ? 1.f : 0.f;
    float z0b = (ve1 > 1.0f) ? 1.f : 0.f;
    ve0 -= z0a * ve0; ve1 -= z0b * ve1;
    float vd0 = vl0 + KM * (il0 - vl0), id0 = KS * il0;
    float vd1 = vl1 + KM * (il1 - vl1), id1 = KS * il1;
    float z1a = (vd0 > 1.0f) ? 1.f : 0.f;
    float z1b = (vd1 > 1.0f) ? 1.f : 0.f;
    vl0 = (1.f - z1a) * vd0; il0 = id0 + z0a;
    vl1 = (1.f - z1b) * vd1; il1 = id1 + z0b;
    f16x2 s; s[0] = (f16)z1a; s[1] = (f16)z1b;
    *(f16x2*)&S0[base + (size_t)t * (128 * 12032)] = s;
  }
}

// ---------- big-tile GEMM for layers 0,1: BM=256, BN=128 (W2 rows), 8 waves ----------
// K-split over blockIdx.z: each z-slice computes Kz columns, writes partial C at
// z*4096*Np. R4-verified m97 2-barrier structure + zero-conflict 8-slot swizzle.
__launch_bounds__(512, 4)
__global__ void gemm_big(const f16* __restrict__ A, const f16* __restrict__ B2,
                         float* __restrict__ C, int Kp, int Np, int Kz) {
  __shared__ f16 sA[256 * 64];  // 32 KiB
  __shared__ f16 sB[128 * 64];  // 16 KiB
  const int tid = threadIdx.x;
  const int lane = tid & 63;
  const int wave = tid >> 6;
  const int wr = wave >> 1;   // 0..3 over M (64 rows each)
  const int wc = wave & 1;    // 0..1 over W2 rows (64 each)

  const int nx = gridDim.x;   // (2*Np)/128
  const int flat = blockIdx.y * nx + blockIdx.x;
  const int cpx = (nx * gridDim.y) >> 3;
  const int id = (flat & 7) * cpx + (flat >> 3);
  const int m0 = (id / nx) * 256;
  const int n0 = (id % nx) * 128;  // W2-row base
  const int z = blockIdx.z;

  f32x4 zero = {0.f, 0.f, 0.f, 0.f};
  f32x4 acc[4][4];
#pragma unroll
  for (int m = 0; m < 4; ++m)
#pragma unroll
    for (int n = 0; n < 4; ++n) acc[m][n] = zero;

  const f16* Abase = A + (size_t)m0 * Kp + (size_t)z * Kz;
  const f16* Bbase = B2 + (size_t)n0 * Kp + (size_t)z * Kz;
  float* Cp = C + (size_t)z * 4096 * Np;
  const int nkt = Kz >> 6;
  for (int kt = 0; kt < nkt; ++kt) {
    __syncthreads();
    const f16* Ab = Abase + (size_t)kt * 64;
    const f16* Bb = Bbase + (size_t)kt * 64;
#pragma unroll
    for (int j = 0; j < 4; ++j) {   // A: 256 rows x 8 chunks = 2048 = 4*512
      int q = j * 512 + tid;
      int r = q >> 3, c = ((q & 7) ^ (r & 7)) * 8;
      __builtin_amdgcn_global_load_lds((const AS1 void*)(Ab + (size_t)r * Kp + c),
                                       (AS3 void*)(&sA[q * 8]), 16, 0, 0);
    }
#pragma unroll
    for (int j = 0; j < 2; ++j) {   // B: 128 rows x 8 chunks = 1024 = 2*512
      int q = j * 512 + tid;
      int r = q >> 3, c = ((q & 7) ^ (r & 7)) * 8;
      __builtin_amdgcn_global_load_lds((const AS1 void*)(Bb + (size_t)r * Kp + c),
                                       (AS3 void*)(&sB[q * 8]), 16, 0, 0);
    }
    __syncthreads();
#pragma unroll
    for (int kk = 0; kk < 2; ++kk) {
      const int lr = lane & 15;
      const int hq = lane >> 4;
      f16x8 af[4], bf[4];
#pragma unroll
      for (int m = 0; m < 4; ++m) {
        int R = wr * 64 + m * 16 + lr;
        int ch = (kk * 4 + hq) ^ (R & 7);
        af[m] = *(const f16x8*)&sA[R * 64 + ch * 8];
      }
#pragma unroll
      for (int n = 0; n < 4; ++n) {
        int R = wc * 64 + n * 16 + lr;
        int ch = (kk * 4 + hq) ^ (R & 7);
        bf[n] = *(const f16x8*)&sB[R * 64 + ch * 8];
      }
#pragma unroll
      for (int m = 0; m < 4; ++m)
#pragma unroll
        for (int n = 0; n < 4; ++n)
          acc[m][n] = __builtin_amdgcn_mfma_f32_16x16x32_f16(af[m], bf[n], acc[m][n], 0, 0, 0);
    }
  }

  // epilogue: fragment pairs (n even = hi16, n odd = lo16 of same logical cols)
  const int lr = lane & 15, lq = lane >> 4;
#pragma unroll
  for (int m = 0; m < 4; ++m)
#pragma unroll
    for (int j = 0; j < 2; ++j) {
      int col = (n0 >> 1) + wc * 32 + j * 16 + lr;
#pragma unroll
      for (int i = 0; i < 4; ++i) {
        int row = m0 + wr * 64 + m * 16 + lq * 4 + i;
        Cp[(size_t)row * Np + col] = acc[m][2 * j][i] + EPS_LO * acc[m][2 * j + 1][i];
      }
    }
}

// ---------- 128x128 4-wave GEMM (round-1 proven) for layers 2..5, K-split ----------
__launch_bounds__(256, 2)
__global__ void gemm_hilo(const f16* __restrict__ A, const f16* __restrict__ Bh,
                          const f16* __restrict__ Bl, float* __restrict__ C,
                          int Kp, int Np, int Kz) {
  __shared__ f16 sA[128 * 64];
  __shared__ f16 sBh[128 * 64];
  __shared__ f16 sBl[128 * 64];
  const int tid = threadIdx.x;
  const int lane = tid & 63;
  const int wave = tid >> 6;
  const int wr = wave >> 1, wc = wave & 1;

  const int nx = gridDim.x;
  const int flat = blockIdx.y * nx + blockIdx.x;
  const int cpx = (nx * gridDim.y) >> 3;
  const int id = (flat & 7) * cpx + (flat >> 3);
  const int m0 = (id / nx) * 128, n0 = (id % nx) * 128;
  const int z = blockIdx.z;

  f32x4 zero = {0.f, 0.f, 0.f, 0.f};
  f32x4 ah[4][4], al[4][4];
#pragma unroll
  for (int m = 0; m < 4; ++m)
#pragma unroll
    for (int n = 0; n < 4; ++n) { ah[m][n] = zero; al[m][n] = zero; }

  const f16* Abase = A + (size_t)m0 * Kp + (size_t)z * Kz;
  const f16* Bhbase = Bh + (size_t)n0 * Kp + (size_t)z * Kz;
  const f16* Blbase = Bl + (size_t)n0 * Kp + (size_t)z * Kz;
  float* Cp = C + (size_t)z * 4096 * Np;
  const int nkt = Kz >> 6;
  for (int kt = 0; kt < nkt; ++kt) {
    __syncthreads();
    const f16* Ab = Abase + (size_t)kt * 64;
    const f16* Bhb = Bhbase + (size_t)kt * 64;
    const f16* Blb = Blbase + (size_t)kt * 64;
#pragma unroll
    for (int j = 0; j < 4; ++j) {
      int q = j * 256 + tid;
      int r = q >> 3;
      int c0 = ((q & 7) ^ (r & 7)) * 8;
      __builtin_amdgcn_global_load_lds((const AS1 void*)(Ab + (size_t)r * Kp + c0),
                                       (AS3 void*)(&sA[q * 8]), 16, 0, 0);
      __builtin_amdgcn_global_load_lds((const AS1 void*)(Bhb + (size_t)r * Kp + c0),
                                       (AS3 void*)(&sBh[q * 8]), 16, 0, 0);
      __builtin_amdgcn_global_load_lds((const AS1 void*)(Blb + (size_t)r * Kp + c0),
                                       (AS3 void*)(&sBl[q * 8]), 16, 0, 0);
    }
    __syncthreads();
#pragma unroll
    for (int kk = 0; kk < 2; ++kk) {
      const int lr = lane & 15;
      const int hq = lane >> 4;
      f16x8 af[4], bhf[4], blf[4];
#pragma unroll
      for (int m = 0; m < 4; ++m) {
        int R = wr * 64 + m * 16 + lr;
        int ch = (kk * 4 + hq) ^ (R & 7);
        af[m] = *(const f16x8*)&sA[R * 64 + ch * 8];
      }
#pragma unroll
      for (int n = 0; n < 4; ++n) {
        int R = wc * 64 + n * 16 + lr;
        int ch = (kk * 4 + hq) ^ (R & 7);
        bhf[n] = *(const f16x8*)&sBh[R * 64 + ch * 8];
        blf[n] = *(const f16x8*)&sBl[R * 64 + ch * 8];
      }
#pragma unroll
      for (int m = 0; m < 4; ++m)
#pragma unroll
        for (int n = 0; n < 4; ++n) {
          ah[m][n] = __builtin_amdgcn_mfma_f32_16x16x32_f16(af[m], bhf[n], ah[m][n], 0, 0, 0);
          al[m][n] = __builtin_amdgcn_mfma_f32_16x16x32_f16(af[m], blf[n], al[m][n], 0, 0, 0);
        }
    }
  }
  const int lr = lane & 15, lq = lane >> 4;
#pragma unroll
  for (int m = 0; m < 4; ++m)
#pragma unroll
    for (int n = 0; n < 4; ++n) {
      int col = n0 + wc * 64 + n * 16 + lr;
#pragma unroll
      for (int i = 0; i < 4; ++i) {
        int row = m0 + wr * 64 + m * 16 + lq * 4 + i;
        Cp[(size_t)row * Np + col] = ah[m][n][i] + EPS_LO * al[m][n][i];
      }
    }
}

// ---------- LI_k + LIF_{k+1}, 2 neurons per thread; sums z-partials ----------
__global__ void li_lif(const float* __restrict__ G, f16* __restrict__ Sn, int Np, int two) {
  int np2 = Np >> 1;
  int idx = blockIdx.x * 256 + threadIdx.x;
  if (idx >= 128 * np2) return;
  int b = idx / np2, n = (idx - b * np2) << 1;
  size_t base = (size_t)b * Np + n;
  size_t stride = (size_t)128 * Np;
  size_t poff = (size_t)4096 * Np;
  float vL0 = 0.f, iL0 = 0.f, vF0 = 0.f, iF0 = 0.f;
  float vL1 = 0.f, iL1 = 0.f, vF1 = 0.f, iF1 = 0.f;
  for (int t = 0; t < 32; ++t) {
    float2 g = *(const float2*)&G[base + t * stride];
    if (two) {
      float2 g2 = *(const float2*)&G[base + t * stride + poff];
      g.x += g2.x; g.y += g2.y;
    }
    float ij0 = iL0 + g.x, ij1 = iL1 + g.y;
    vL0 = vL0 + KM * (ij0 - vL0); iL0 = KS * ij0;
    vL1 = vL1 + KM * (ij1 - vL1); iL1 = KS * ij1;
    float vd0 = vF0 + KM * (iF0 - vF0), id0 = KS * iF0;
    float vd1 = vF1 + KM * (iF1 - vF1), id1 = KS * iF1;
    float z0 = (vd0 > 1.0f) ? 1.f : 0.f;
    float z1 = (vd1 > 1.0f) ? 1.f : 0.f;
    vF0 = (1.f - z0) * vd0; iF0 = id0 + vL0;
    vF1 = (1.f - z1) * vd1; iF1 = id1 + vL1;
    f16x2 s; s[0] = (f16)z0; s[1] = (f16)z1;
    *(f16x2*)&Sn[base + t * stride] = s;
  }
}

// ---------- LI5 scan + max over t + log_softmax; sums z-partials ----------
__global__ void final_k(const float* __restrict__ G, float* __restrict__ out, int two) {
  int b = blockIdx.x;
  int n = threadIdx.x;
  size_t poff = (size_t)4096 * 128;
  float vL = 0.f, iL = 0.f, mx = -3.4e38f;
  for (int t = 0; t < 32; ++t) {
    size_t ix = (size_t)(t * 128 + b) * 128 + n;
    float g = G[ix];
    if (two) g += G[ix + poff];
    float ij = iL + g;
    vL = vL + KM * (ij - vL);
    iL = KS * ij;
    mx = fmaxf(mx, vL);
  }
  float v = (n < 10) ? mx : -3.4e38f;
  float M = v;
#pragma unroll
  for (int s = 1; s < 16; s <<= 1) M = fmaxf(M, __shfl_xor(M, s));
  float e = (n < 10) ? expf(v - M) : 0.f;
  float sum = e;
#pragma unroll
  for (int s = 1; s < 16; s <<= 1) sum += __shfl_xor(sum, s);
  if (n < 10) out[b * 10 + n] = v - M - logf(sum);
}

extern "C" void kernel_launch(void* const* d_in, const int* in_sizes, int n_in,
                              void* d_out, int out_size, void* d_ws, size_t ws_size,
                              hipStream_t stream) {
  const float* img = (const float*)d_in[0];
  static const int Nr[6]  = {2000, 1500, 1000, 500, 100, 10};
  static const int Kr[6]  = {12000, 2000, 1500, 1000, 500, 100};
  static const int Npd[6] = {2048, 1536, 1024, 512, 128, 128};
  static const int Kpd[6] = {12032, 2048, 1536, 1024, 512, 128};

  char* p = (char*)d_ws;
  f16* wa[6];  // k<=1: W2 interleaved [2*Npd][Kpd]; k>=2: whi
  f16* wb[6];  // k>=2: wlo
  for (int k = 0; k < 6; ++k) {
    if (k < 2) {
      wa[k] = (f16*)p; wb[k] = wa[k];
      p += (size_t)2 * Npd[k] * Kpd[k] * 2;
    } else {
      wa[k] = (f16*)p; p += (size_t)Npd[k] * Kpd[k] * 2;
      wb[k] = (f16*)p; p += (size_t)Npd[k] * Kpd[k] * 2;
    }
  }
  f16* S = (f16*)p;  p += (size_t)4096 * 12032 * 2;  // spike buffer (max width layer 0)
  float* G = (float*)p;                              // partial GEMM-out: z-slices contiguous
  size_t need1 = (size_t)(p - (char*)d_ws) + (size_t)4096 * 2048 * 4;      // z=1 footprint
  size_t need2 = need1 + (size_t)4096 * 2048 * 4;                          // z=2 footprint
  const int nz = (ws_size >= need2) ? 2 : 1;
  (void)need1;

  PrepArgs pa;
  int nb = 0;
  for (int k = 0; k < 6; ++k) {
    pa.W[k] = (const float*)d_in[k + 1];
    pa.dsth[k] = wa[k];
    pa.dstl[k] = wb[k];
    pa.Nr[k] = Nr[k]; pa.Kr[k] = Kr[k]; pa.Kp[k] = Kpd[k]; pa.Npd[k] = Npd[k];
    pa.inter[k] = (k < 2) ? 1 : 0;
    pa.boff[k] = nb;
    nb += ((Npd[k] * Kpd[k]) >> 2) / 256;  // exact for all layers
  }
  pa.boff[6] = nb;
  prep_w_all<<<nb, 256, 0, stream>>>(pa);

  enc_lif0<<<(128 * 6016 + 255) / 256, 256, 0, stream>>>(img, S);
  for (int k = 0; k < 6; ++k) {
    int Kz = Kpd[k] / nz;
    if (k < 2) {
      gemm_big<<<dim3(2 * Npd[k] / 128, 16, nz), dim3(512), 0, stream>>>(
          S, wa[k], G, Kpd[k], Npd[k], Kz);
    } else {
      gemm_hilo<<<dim3(Npd[k] / 128, 32, nz), dim3(256), 0, stream>>>(
          S, wa[k], wb[k], G, Kpd[k], Npd[k], Kz);
    }
    if (k < 5)
      li_lif<<<(128 * (Npd[k] >> 1) + 255) / 256, 256, 0, stream>>>(G, S, Npd[k], nz - 1);
  }
  final_k<<<128, 64, 0, stream>>>(G, (float*)d_out, nz - 1);
}

// Round 7
// 319.695 us; speedup vs baseline: 1.8214x; 1.8214x over previous
//
#include <hip/hip_runtime.h>

typedef _Float16 f16;
typedef _Float16 f16x2 __attribute__((ext_vector_type(2)));
typedef _Float16 f16x4 __attribute__((ext_vector_type(4)));
typedef _Float16 f16x8 __attribute__((ext_vector_type(8)));
typedef float f32x4 __attribute__((ext_vector_type(4)));
typedef unsigned int uint;

#define KM 0.1f   // DT * TAU_MEM_INV
#define KS 0.8f   // 1 - DT * TAU_SYN_INV
#define AS1 __attribute__((address_space(1)))
#define AS3 __attribute__((address_space(3)))
#define EPS_LO 2.44140625e-4f  // 2^-12

// ---------- E1: enc+LIF0 sim -> spike bitmask Z[b][f] + column flags ----------
__global__ void enc_flags(const float* __restrict__ img, uint* __restrict__ Z,
                          uint* __restrict__ flags) {
  int idx = blockIdx.x * 256 + threadIdx.x;
  if (idx >= 128 * 6000) return;
  int b = idx / 6000, f = (idx - b * 6000) << 1;
  float2 t2 = *(const float2*)&img[b * 12000 + f];
  float x0 = t2.x, x1 = t2.y;
  float ve0 = 0.f, vl0 = 0.f, il0 = 0.f;
  float ve1 = 0.f, vl1 = 0.f, il1 = 0.f;
  uint m0 = 0u, m1 = 0u;
  for (int t = 0; t < 32; ++t) {
    ve0 = ve0 + KM * (x0 - ve0);
    ve1 = ve1 + KM * (x1 - ve1);
    float z0a = (ve0 > 1.0f) ? 1.f : 0.f;
    float z0b = (ve1 > 1.0f) ? 1.f : 0.f;
    ve0 -= z0a * ve0; ve1 -= z0b * ve1;
    float vd0 = vl0 + KM * (il0 - vl0), id0 = KS * il0;
    float vd1 = vl1 + KM * (il1 - vl1), id1 = KS * il1;
    float z1a = (vd0 > 1.0f) ? 1.f : 0.f;
    float z1b = (vd1 > 1.0f) ? 1.f : 0.f;
    m0 |= (vd0 > 1.0f) ? (1u << t) : 0u;
    m1 |= (vd1 > 1.0f) ? (1u << t) : 0u;
    vl0 = (1.f - z1a) * vd0; il0 = id0 + z0a;
    vl1 = (1.f - z1b) * vd1; il1 = id1 + z0b;
  }
  Z[b * 12032 + f] = m0;
  Z[b * 12032 + f + 1] = m1;
  uint mask = (m0 ? 1u : 0u) << (f & 31) | (m1 ? 1u : 0u) << ((f & 31) + 1);
  if (mask) atomicOr(&flags[f >> 5], mask);
}

// ---------- E2: popcount scan over 376 flag words -> sorted colidx, meta={K', Kpc} ----------
__global__ void scan_cols(const uint* __restrict__ flags, int* __restrict__ colidx,
                          int* __restrict__ meta) {
  __shared__ int cnt[512];
  int t = threadIdx.x;
  uint w = (t < 376) ? flags[t] : 0u;
  cnt[t] = __popc(w);
  __syncthreads();
  for (int off = 1; off < 512; off <<= 1) {
    int v = cnt[t];
    int u = (t >= off) ? cnt[t - off] : 0;
    __syncthreads();
    cnt[t] = v + u;
    __syncthreads();
  }
  int base = cnt[t] - __popc(w);  // exclusive prefix
  uint ww = w;
  int r = 0;
  while (ww) {
    int p = __ffs(ww) - 1;
    colidx[base + r] = t * 32 + p;
    ww &= ww - 1;
    ++r;
  }
  if (t == 511) {
    int K = cnt[511];
    meta[0] = K;
    meta[1] = (K + 63) & ~63;
  }
}

// ---------- E3: compacted A'[4096][Kpc] from Z bitmasks (no FP, exact) ----------
__global__ void spike_gather(const uint* __restrict__ Z, f16* __restrict__ A,
                             const int* __restrict__ colidx, const int* __restrict__ meta) {
  int K = meta[0], Kpc = meta[1];
  if (Kpc == 0) return;
  int jp = Kpc >> 1;
  int total = 128 * jp;
  for (int i = blockIdx.x * 256 + threadIdx.x; i < total; i += gridDim.x * 256) {
    int b = i / jp, j = (i - b * jp) << 1;
    uint m0 = (j < K) ? Z[b * 12032 + colidx[j]] : 0u;
    uint m1 = (j + 1 < K) ? Z[b * 12032 + colidx[j + 1]] : 0u;
    size_t base = (size_t)b * Kpc + j;
    size_t stride = (size_t)128 * Kpc;
    for (int t = 0; t < 32; ++t) {
      f16x2 s;
      s[0] = (f16)(float)((m0 >> t) & 1u);
      s[1] = (f16)(float)((m1 >> t) & 1u);
      *(f16x2*)&A[base + (size_t)t * stride] = s;
    }
  }
}

// ---------- P0: gather-prep layer-0 weights at compacted columns (interleaved hi/lo) ----------
__global__ void prep_w0_gather(const float* __restrict__ W, f16* __restrict__ dst,
                               const int* __restrict__ colidx, const int* __restrict__ meta) {
  int K = meta[0], Kpc = meta[1];
  if (Kpc == 0) return;
  int kq = Kpc >> 2;
  int total = 4096 * kq;
  for (int i = blockIdx.x * 256 + threadIdx.x; i < total; i += gridDim.x * 256) {
    int r2 = i / kq;
    int j4 = (i - r2 * kq) << 2;
    int B2 = r2 >> 4;
    int o = (B2 >> 1) * 16 + (r2 & 15);
    int isLo = B2 & 1;
    f16x4 out;
#pragma unroll
    for (int e = 0; e < 4; ++e) {
      int j = j4 + e;
      float w = 0.f;
      if (j < K && o < 2000) w = W[o * 12000 + colidx[j]];
      f16 h = (f16)w;
      float hf = (float)h;
      if (__builtin_fabsf(hf) < 6.103515625e-05f) { h = (f16)0.f; hf = 0.f; }
      f16 l = (f16)((w - hf) * 4096.0f);
      out[e] = isLo ? l : h;
    }
    *(f16x4*)&dst[(size_t)r2 * Kpc + j4] = out;
  }
}

// ---------- weight prep for layers 1..5 ----------
struct PrepArgs {
  const float* W[5];
  f16* dsth[5];
  f16* dstl[5];
  int Nr[5], Kr[5], Kp[5], Npd[5];
  int boff[6];
  int inter[5];
};

__global__ void prep_w_all(PrepArgs a) {
  int blk = blockIdx.x;
  int k = 0;
#pragma unroll
  for (int j = 0; j < 4; ++j) k += (blk >= a.boff[j + 1]) ? 1 : 0;
  int i = (blk - a.boff[k]) * 256 + threadIdx.x;
  int Kp = a.Kp[k];
  int kp4 = Kp >> 2;
  int total4 = a.Npd[k] * kp4;
  if (i >= total4) return;
  int o = i / kp4, f = (i - o * kp4) << 2;
  float w[4] = {0.f, 0.f, 0.f, 0.f};
  if (o < a.Nr[k] && f < a.Kr[k]) {
    float4 t = *(const float4*)&a.W[k][(size_t)o * a.Kr[k] + f];
    w[0] = t.x; w[1] = t.y; w[2] = t.z; w[3] = t.w;
  }
  f16x4 h4, l4;
#pragma unroll
  for (int e = 0; e < 4; ++e) {
    f16 h = (f16)w[e];
    float hf = (float)h;
    if (__builtin_fabsf(hf) < 6.103515625e-05f) { h = (f16)0.f; hf = 0.f; }
    h4[e] = h;
    l4[e] = (f16)((w[e] - hf) * 4096.0f);
  }
  if (a.inter[k]) {
    int r2 = ((o >> 4) << 5) + (o & 15);
    *(f16x4*)&a.dsth[k][(size_t)r2 * Kp + f] = h4;
    *(f16x4*)&a.dsth[k][(size_t)(r2 + 16) * Kp + f] = l4;
  } else {
    *(f16x4*)&a.dsth[k][(size_t)o * Kp + f] = h4;
    *(f16x4*)&a.dstl[k][(size_t)o * Kp + f] = l4;
  }
}

// ---------- big-tile GEMM (layers 0,1): BM=256, BN=128 W2-rows, 8 waves ----------
// K from device memory when kpcp != nullptr (layer 0 compacted K).
__launch_bounds__(512, 4)
__global__ void gemm_big(const f16* __restrict__ A, const f16* __restrict__ B2,
                         float* __restrict__ C, const int* __restrict__ kpcp,
                         int KpFixed, int Np) {
  __shared__ f16 sA[256 * 64];  // 32 KiB
  __shared__ f16 sB[128 * 64];  // 16 KiB
  const int Kp = kpcp ? kpcp[1] : KpFixed;
  const int tid = threadIdx.x;
  const int lane = tid & 63;
  const int wave = tid >> 6;
  const int wr = wave >> 1;
  const int wc = wave & 1;

  const int nx = gridDim.x;
  const int flat = blockIdx.y * nx + blockIdx.x;
  const int cpx = (nx * gridDim.y) >> 3;
  const int id = (flat & 7) * cpx + (flat >> 3);
  const int m0 = (id / nx) * 256;
  const int n0 = (id % nx) * 128;

  f32x4 zero = {0.f, 0.f, 0.f, 0.f};
  f32x4 acc[4][4];
#pragma unroll
  for (int m = 0; m < 4; ++m)
#pragma unroll
    for (int n = 0; n < 4; ++n) acc[m][n] = zero;

  const f16* Abase = A + (size_t)m0 * Kp;
  const f16* Bbase = B2 + (size_t)n0 * Kp;
  const int nkt = Kp >> 6;
  for (int kt = 0; kt < nkt; ++kt) {
    __syncthreads();
    const f16* Ab = Abase + (size_t)kt * 64;
    const f16* Bb = Bbase + (size_t)kt * 64;
#pragma unroll
    for (int j = 0; j < 4; ++j) {
      int q = j * 512 + tid;
      int r = q >> 3, c = ((q & 7) ^ (r & 7)) * 8;
      __builtin_amdgcn_global_load_lds((const AS1 void*)(Ab + (size_t)r * Kp + c),
                                       (AS3 void*)(&sA[q * 8]), 16, 0, 0);
    }
#pragma unroll
    for (int j = 0; j < 2; ++j) {
      int q = j * 512 + tid;
      int r = q >> 3, c = ((q & 7) ^ (r & 7)) * 8;
      __builtin_amdgcn_global_load_lds((const AS1 void*)(Bb + (size_t)r * Kp + c),
                                       (AS3 void*)(&sB[q * 8]), 16, 0, 0);
    }
    __syncthreads();
#pragma unroll
    for (int kk = 0; kk < 2; ++kk) {
      const int lr = lane & 15;
      const int hq = lane >> 4;
      f16x8 af[4], bf[4];
#pragma unroll
      for (int m = 0; m < 4; ++m) {
        int R = wr * 64 + m * 16 + lr;
        int ch = (kk * 4 + hq) ^ (R & 7);
        af[m] = *(const f16x8*)&sA[R * 64 + ch * 8];
      }
#pragma unroll
      for (int n = 0; n < 4; ++n) {
        int R = wc * 64 + n * 16 + lr;
        int ch = (kk * 4 + hq) ^ (R & 7);
        bf[n] = *(const f16x8*)&sB[R * 64 + ch * 8];
      }
#pragma unroll
      for (int m = 0; m < 4; ++m)
#pragma unroll
        for (int n = 0; n < 4; ++n)
          acc[m][n] = __builtin_amdgcn_mfma_f32_16x16x32_f16(af[m], bf[n], acc[m][n], 0, 0, 0);
    }
  }

  const int lr = lane & 15, lq = lane >> 4;
#pragma unroll
  for (int m = 0; m < 4; ++m)
#pragma unroll
    for (int j = 0; j < 2; ++j) {
      int col = (n0 >> 1) + wc * 32 + j * 16 + lr;
#pragma unroll
      for (int i = 0; i < 4; ++i) {
        int row = m0 + wr * 64 + m * 16 + lq * 4 + i;
        C[(size_t)row * Np + col] = acc[m][2 * j][i] + EPS_LO * acc[m][2 * j + 1][i];
      }
    }
}

// ---------- 128x128 4-wave GEMM (layers 2..5) ----------
__launch_bounds__(256, 2)
__global__ void gemm_hilo(const f16* __restrict__ A, const f16* __restrict__ Bh,
                          const f16* __restrict__ Bl, float* __restrict__ C,
                          int Kp, int Np) {
  __shared__ f16 sA[128 * 64];
  __shared__ f16 sBh[128 * 64];
  __shared__ f16 sBl[128 * 64];
  const int tid = threadIdx.x;
  const int lane = tid & 63;
  const int wave = tid >> 6;
  const int wr = wave >> 1, wc = wave & 1;

  const int nx = gridDim.x;
  const int flat = blockIdx.y * nx + blockIdx.x;
  const int cpx = (nx * gridDim.y) >> 3;
  const int id = (flat & 7) * cpx + (flat >> 3);
  const int m0 = (id / nx) * 128, n0 = (id % nx) * 128;

  f32x4 zero = {0.f, 0.f, 0.f, 0.f};
  f32x4 ah[4][4], al[4][4];
#pragma unroll
  for (int m = 0; m < 4; ++m)
#pragma unroll
    for (int n = 0; n < 4; ++n) { ah[m][n] = zero; al[m][n] = zero; }

  const int nkt = Kp >> 6;
  for (int kt = 0; kt < nkt; ++kt) {
    __syncthreads();
    const f16* Ab = A + (size_t)m0 * Kp + (size_t)kt * 64;
    const f16* Bhb = Bh + (size_t)n0 * Kp + (size_t)kt * 64;
    const f16* Blb = Bl + (size_t)n0 * Kp + (size_t)kt * 64;
#pragma unroll
    for (int j = 0; j < 4; ++j) {
      int q = j * 256 + tid;
      int r = q >> 3;
      int c0 = ((q & 7) ^ (r & 7)) * 8;
      __builtin_amdgcn_global_load_lds((const AS1 void*)(Ab + (size_t)r * Kp + c0),
                                       (AS3 void*)(&sA[q * 8]), 16, 0, 0);
      __builtin_amdgcn_global_load_lds((const AS1 void*)(Bhb + (size_t)r * Kp + c0),
                                       (AS3 void*)(&sBh[q * 8]), 16, 0, 0);
      __builtin_amdgcn_global_load_lds((const AS1 void*)(Blb + (size_t)r * Kp + c0),
                                       (AS3 void*)(&sBl[q * 8]), 16, 0, 0);
    }
    __syncthreads();
#pragma unroll
    for (int kk = 0; kk < 2; ++kk) {
      const int lr = lane & 15;
      const int hq = lane >> 4;
      f16x8 af[4], bhf[4], blf[4];
#pragma unroll
      for (int m = 0; m < 4; ++m) {
        int R = wr * 64 + m * 16 + lr;
        int ch = (kk * 4 + hq) ^ (R & 7);
        af[m] = *(const f16x8*)&sA[R * 64 + ch * 8];
      }
#pragma unroll
      for (int n = 0; n < 4; ++n) {
        int R = wc * 64 + n * 16 + lr;
        int ch = (kk * 4 + hq) ^ (R & 7);
        bhf[n] = *(const f16x8*)&sBh[R * 64 + ch * 8];
        blf[n] = *(const f16x8*)&sBl[R * 64 + ch * 8];
      }
#pragma unroll
      for (int m = 0; m < 4; ++m)
#pragma unroll
        for (int n = 0; n < 4; ++n) {
          ah[m][n] = __builtin_amdgcn_mfma_f32_16x16x32_f16(af[m], bhf[n], ah[m][n], 0, 0, 0);
          al[m][n] = __builtin_amdgcn_mfma_f32_16x16x32_f16(af[m], blf[n], al[m][n], 0, 0, 0);
        }
    }
  }
  const int lr = lane & 15, lq = lane >> 4;
#pragma unroll
  for (int m = 0; m < 4; ++m)
#pragma unroll
    for (int n = 0; n < 4; ++n) {
      int col = n0 + wc * 64 + n * 16 + lr;
#pragma unroll
      for (int i = 0; i < 4; ++i) {
        int row = m0 + wr * 64 + m * 16 + lq * 4 + i;
        C[(size_t)row * Np + col] = ah[m][n][i] + EPS_LO * al[m][n][i];
      }
    }
}

// ---------- LI_k + LIF_{k+1}, 2 neurons per thread ----------
__global__ void li_lif(const float* __restrict__ G, f16* __restrict__ Sn, int Np) {
  int np2 = Np >> 1;
  int idx = blockIdx.x * 256 + threadIdx.x;
  if (idx >= 128 * np2) return;
  int b = idx / np2, n = (idx - b * np2) << 1;
  size_t base = (size_t)b * Np + n;
  size_t stride = (size_t)128 * Np;
  float vL0 = 0.f, iL0 = 0.f, vF0 = 0.f, iF0 = 0.f;
  float vL1 = 0.f, iL1 = 0.f, vF1 = 0.f, iF1 = 0.f;
  for (int t = 0; t < 32; ++t) {
    float2 g = *(const float2*)&G[base + t * stride];
    float ij0 = iL0 + g.x, ij1 = iL1 + g.y;
    vL0 = vL0 + KM * (ij0 - vL0); iL0 = KS * ij0;
    vL1 = vL1 + KM * (ij1 - vL1); iL1 = KS * ij1;
    float vd0 = vF0 + KM * (iF0 - vF0), id0 = KS * iF0;
    float vd1 = vF1 + KM * (iF1 - vF1), id1 = KS * iF1;
    float z0 = (vd0 > 1.0f) ? 1.f : 0.f;
    float z1 = (vd1 > 1.0f) ? 1.f : 0.f;
    vF0 = (1.f - z0) * vd0; iF0 = id0 + vL0;
    vF1 = (1.f - z1) * vd1; iF1 = id1 + vL1;
    f16x2 s; s[0] = (f16)z0; s[1] = (f16)z1;
    *(f16x2*)&Sn[base + t * stride] = s;
  }
}

// ---------- LI5 scan + max over t + log_softmax ----------
__global__ void final_k(const float* __restrict__ G, float* __restrict__ out) {
  int b = blockIdx.x;
  int n = threadIdx.x;
  float vL = 0.f, iL = 0.f, mx = -3.4e38f;
  for (int t = 0; t < 32; ++t) {
    float g = G[(size_t)(t * 128 + b) * 128 + n];
    float ij = iL + g;
    vL = vL + KM * (ij - vL);
    iL = KS * ij;
    mx = fmaxf(mx, vL);
  }
  float v = (n < 10) ? mx : -3.4e38f;
  float M = v;
#pragma unroll
  for (int s = 1; s < 16; s <<= 1) M = fmaxf(M, __shfl_xor(M, s));
  float e = (n < 10) ? expf(v - M) : 0.f;
  float sum = e;
#pragma unroll
  for (int s = 1; s < 16; s <<= 1) sum += __shfl_xor(sum, s);
  if (n < 10) out[b * 10 + n] = v - M - logf(sum);
}

extern "C" void kernel_launch(void* const* d_in, const int* in_sizes, int n_in,
                              void* d_out, int out_size, void* d_ws, size_t ws_size,
                              hipStream_t stream) {
  const float* img = (const float*)d_in[0];
  static const int Nr[6]  = {2000, 1500, 1000, 500, 100, 10};
  static const int Kr[6]  = {12000, 2000, 1500, 1000, 500, 100};
  static const int Npd[6] = {2048, 1536, 1024, 512, 128, 128};
  static const int Kpd[6] = {12032, 2048, 1536, 1024, 512, 128};

  char* p = (char*)d_ws;
  f16* wa[6];  // k<=1: interleaved W2; k>=2: whi
  f16* wb[6];  // k>=2: wlo
  // layer 0 compact interleaved weights, max size [4096][12032]
  wa[0] = (f16*)p; wb[0] = wa[0];
  p += (size_t)4096 * 12032 * 2;
  for (int k = 1; k < 6; ++k) {
    if (k < 2) {
      wa[k] = (f16*)p; wb[k] = wa[k];
      p += (size_t)2 * Npd[k] * Kpd[k] * 2;
    } else {
      wa[k] = (f16*)p; p += (size_t)Npd[k] * Kpd[k] * 2;
      wb[k] = (f16*)p; p += (size_t)Npd[k] * Kpd[k] * 2;
    }
  }
  f16* S = (f16*)p;  p += (size_t)4096 * 12032 * 2;  // compact A (L0), then spike buffers
  float* G = (float*)p; p += (size_t)4096 * 2048 * 4;
  uint* Z = (uint*)p; p += (size_t)128 * 12032 * 4;  // spike bitmasks
  uint* flags = (uint*)p; p += 376 * 4;
  int* colidx = (int*)p; p += 12032 * 4;
  int* meta = (int*)p; p += 2 * 4;

  // --- layer-0 column compaction chain ---
  hipMemsetAsync(flags, 0, 376 * 4, stream);
  enc_flags<<<(128 * 6000 + 255) / 256, 256, 0, stream>>>(img, Z, flags);
  scan_cols<<<1, 512, 0, stream>>>(flags, colidx, meta);
  spike_gather<<<1024, 256, 0, stream>>>(Z, S, colidx, meta);
  prep_w0_gather<<<2048, 256, 0, stream>>>((const float*)d_in[1], wa[0], colidx, meta);

  // --- layers 1..5 weight prep ---
  PrepArgs pa;
  int nb = 0;
  for (int k = 1; k < 6; ++k) {
    int kk = k - 1;
    pa.W[kk] = (const float*)d_in[k + 1];
    pa.dsth[kk] = wa[k];
    pa.dstl[kk] = wb[k];
    pa.Nr[kk] = Nr[k]; pa.Kr[kk] = Kr[k]; pa.Kp[kk] = Kpd[k]; pa.Npd[kk] = Npd[k];
    pa.inter[kk] = (k < 2) ? 1 : 0;
    pa.boff[kk] = nb;
    nb += ((Npd[k] * Kpd[k]) >> 2) / 256;
  }
  pa.boff[5] = nb;
  prep_w_all<<<nb, 256, 0, stream>>>(pa);

  // --- layer pipeline ---
  for (int k = 0; k < 6; ++k) {
    if (k == 0) {
      gemm_big<<<dim3(2 * Npd[0] / 128, 16), dim3(512), 0, stream>>>(
          S, wa[0], G, meta, 0, Npd[0]);
    } else if (k == 1) {
      gemm_big<<<dim3(2 * Npd[1] / 128, 16), dim3(512), 0, stream>>>(
          S, wa[1], G, nullptr, Kpd[1], Npd[1]);
    } else {
      gemm_hilo<<<dim3(Npd[k] / 128, 32), dim3(256), 0, stream>>>(
          S, wa[k], wb[k], G, Kpd[k], Npd[k]);
    }
    if (k < 5)
      li_lif<<<(128 * (Npd[k] >> 1) + 255) / 256, 256, 0, stream>>>(G, S, Npd[k]);
  }
  final_k<<<128, 64, 0, stream>>>(G, (float*)d_out);
}